// Round 2
// baseline (1105.542 us; speedup 1.0000x reference)
//
#include <hip/hip_runtime.h>
#include <cstdint>
#include <cstddef>

// Device buffers: ALL fp32 (in_npz size 166 MB == fp32 raw 179 MB compressed;
// bf16 would be 90 MB). Compute pipeline: convert once to bf16 in ws, MFMA in
// bf16 with fp32 accum, final GEMM accumulates into fp32 d_out.
typedef __bf16 bf16_t;
typedef float f32x4 __attribute__((ext_vector_type(4)));
typedef __bf16 bf16x8 __attribute__((ext_vector_type(8)));

#define MFMA_BF16(a, b, c) __builtin_amdgcn_mfma_f32_16x16x32_bf16((a), (b), (c), 0, 0, 0)

// ---------------------------------------------------------------------------
// fp32 -> bf16 convert, 8 elements/thread
// ---------------------------------------------------------------------------
__global__ void convert_kernel(const float* __restrict__ src,
                               bf16_t* __restrict__ dst, int n8)
{
    const int i = blockIdx.x * blockDim.x + threadIdx.x;
    if (i < n8) {
        const float4* s = (const float4*)src + (size_t)i * 2;
        const float4 a = s[0], b = s[1];
        bf16x8 v = {(bf16_t)a.x, (bf16_t)a.y, (bf16_t)a.z, (bf16_t)a.w,
                    (bf16_t)b.x, (bf16_t)b.y, (bf16_t)b.z, (bf16_t)b.w};
        *((bf16x8*)dst + i) = v;
    }
}

// ---------------------------------------------------------------------------
// C[M,N] = scale * (A[M,K] @ W[N,K]^T)   (+ C if accumulate)
// 128x128 tile, 4 waves in 2x2, each wave 64x64 via 4x4 frags of 16x16x32.
// Verified fragment layouts (learn_hip m89/m91):
//   A frag: lane l -> A[m = l&15][k = 8*(l>>4)+e]
//   B frag: lane l -> B[k = 8*(l>>4)+e][n = l&15] = W[n][k] (W row-major)
//   D frag: lane l -> D[row = 4*(l>>4)+r][col = l&15]
// ---------------------------------------------------------------------------
template <typename CT>
__global__ __launch_bounds__(256) void gemm_bt(const bf16_t* __restrict__ A,
                                               const bf16_t* __restrict__ W,
                                               CT* C,
                                               int M, int N, int K,
                                               const float* __restrict__ scale_ptr,
                                               int accumulate)
{
    __shared__ bf16_t As[128 * 32];
    __shared__ bf16_t Ws[128 * 32];
    const int t = threadIdx.x;
    const int lane = t & 63;
    const int w = t >> 6;
    const int wr = (w >> 1) * 64;   // wave row offset in tile
    const int wc = (w & 1) * 64;    // wave col offset in tile
    const int tm = blockIdx.x * 128, tn = blockIdx.y * 128;
    const int l15 = lane & 15, l4 = lane >> 4;

    const f32x4 fzero = {0.f, 0.f, 0.f, 0.f};
    f32x4 acc[4][4];
    for (int i = 0; i < 4; ++i)
        for (int j = 0; j < 4; ++j) acc[i][j] = fzero;

    // staging map: thread t covers tile elements [t*8, t*8+8) and +2048
    const int f0 = t * 8, f1 = f0 + 2048;
    const int ar0 = f0 >> 5, ac0 = f0 & 31;
    const int ar1 = f1 >> 5, ac1 = f1 & 31;

    for (int kb = 0; kb < K; kb += 32) {
        bf16x8 a0 = *(const bf16x8*)(A + (size_t)(tm + ar0) * K + kb + ac0);
        bf16x8 a1 = *(const bf16x8*)(A + (size_t)(tm + ar1) * K + kb + ac1);
        bf16x8 w0 = *(const bf16x8*)(W + (size_t)(tn + ar0) * K + kb + ac0);
        bf16x8 w1 = *(const bf16x8*)(W + (size_t)(tn + ar1) * K + kb + ac1);
        __syncthreads();
        *(bf16x8*)(As + f0) = a0;
        *(bf16x8*)(As + f1) = a1;
        *(bf16x8*)(Ws + f0) = w0;
        *(bf16x8*)(Ws + f1) = w1;
        __syncthreads();
        bf16x8 af[4], bfr[4];
#pragma unroll
        for (int i = 0; i < 4; ++i)
            af[i] = *(const bf16x8*)(As + (wr + i * 16 + l15) * 32 + l4 * 8);
#pragma unroll
        for (int j = 0; j < 4; ++j)
            bfr[j] = *(const bf16x8*)(Ws + (wc + j * 16 + l15) * 32 + l4 * 8);
#pragma unroll
        for (int i = 0; i < 4; ++i)
#pragma unroll
            for (int j = 0; j < 4; ++j)
                acc[i][j] = MFMA_BF16(af[i], bfr[j], acc[i][j]);
    }

    const float scale = scale_ptr ? scale_ptr[0] : 1.0f;
    for (int i = 0; i < 4; ++i) {
        for (int j = 0; j < 4; ++j) {
            const int col = tn + wc + j * 16 + l15;
            for (int r = 0; r < 4; ++r) {
                const int row = tm + wr + i * 16 + l4 * 4 + r;
                const size_t idx = (size_t)row * N + col;
                float v = acc[i][j][r] * scale;
                if (accumulate) v += (float)C[idx];
                C[idx] = (CT)v;
            }
        }
    }
}

// ---------------------------------------------------------------------------
// Flash attention over projected Q/K/V stored as (L*B, 768) rows (row = l*B+b,
// head h occupies cols [h*96, h*96+96)). ctx is written IN PLACE over QC:
// each block reads exactly the rows/cols it later writes (Q frags hoisted to
// registers first), and no other block touches those elements.
// Block: 256 thr = 4 waves; wave w owns 16 q-rows. Grid: (qtile=8, h=8, b=32).
// ---------------------------------------------------------------------------
__global__ __launch_bounds__(256) void attn_kernel(bf16_t* QC,
                                                   const bf16_t* __restrict__ Kp,
                                                   const bf16_t* __restrict__ Vp)
{
    constexpr int B = 32, HD = 96, D = 768;
    __shared__ bf16_t Ks[64 * 96];     // K tile row-major [kpos][c]
    __shared__ bf16_t Vt[96 * 64];     // V tile transposed [c][kpos]
    __shared__ bf16_t Ps[4 * 16 * 64]; // per-wave P [16 rows][64 kpos]

    const int qt = blockIdx.x, h = blockIdx.y, b = blockIdx.z;
    const int t = threadIdx.x, lane = t & 63, w = t >> 6;
    const int l15 = lane & 15, l4 = lane >> 4;
    const int q0 = qt * 64 + w * 16;   // wave's first q row
    const float qk_scale = 0.10206207261596575f; // 1/sqrt(96)

    // Q fragments for this wave's 16 rows (3 k-steps of 32 cover hd=96)
    bf16x8 aq[3];
#pragma unroll
    for (int kk = 0; kk < 3; ++kk)
        aq[kk] = *(const bf16x8*)(QC + ((size_t)(q0 + l15) * B + b) * D + h * HD + kk * 32 + l4 * 8);

    const f32x4 fzero = {0.f, 0.f, 0.f, 0.f};
    f32x4 o[6];
#pragma unroll
    for (int f = 0; f < 6; ++f) o[f] = fzero;
    float mr[4], lr[4];
#pragma unroll
    for (int r = 0; r < 4; ++r) { mr[r] = -1e30f; lr[r] = 0.f; }

    for (int kt = 0; kt < 8; ++kt) {
        const int k0 = kt * 64;
        // stage K (row-major) and V (transposed) tiles: 64x96 each
        bf16x8 kreg[3], vreg[3];
        int rrs[3], ccs[3];
#pragma unroll
        for (int i = 0; i < 3; ++i) {
            const int f = t * 8 + i * 2048;
            const int rr = f / 96, cc = f % 96;
            rrs[i] = rr; ccs[i] = cc;
            kreg[i] = *(const bf16x8*)(Kp + ((size_t)(k0 + rr) * B + b) * D + h * HD + cc);
            vreg[i] = *(const bf16x8*)(Vp + ((size_t)(k0 + rr) * B + b) * D + h * HD + cc);
        }
        __syncthreads();   // previous iteration's reads done
#pragma unroll
        for (int i = 0; i < 3; ++i) {
            *(bf16x8*)(Ks + rrs[i] * 96 + ccs[i]) = kreg[i];
#pragma unroll
            for (int j = 0; j < 8; ++j)
                Vt[(ccs[i] + j) * 64 + rrs[i]] = vreg[i][j];
        }
        __syncthreads();

        // S = Q @ K^T  (wave's 16 rows x 64 kpos)
        f32x4 s[4];
#pragma unroll
        for (int n = 0; n < 4; ++n) {
            s[n] = fzero;
#pragma unroll
            for (int kk = 0; kk < 3; ++kk) {
                bf16x8 kf = *(const bf16x8*)(Ks + (n * 16 + l15) * 96 + kk * 32 + l4 * 8);
                s[n] = MFMA_BF16(aq[kk], kf, s[n]);
            }
        }

        // online softmax; lane owns rows (4*l4 + r), one col per frag (l15)
        float pm[4];
#pragma unroll
        for (int r = 0; r < 4; ++r) {
            float v = fmaxf(fmaxf(s[0][r], s[1][r]), fmaxf(s[2][r], s[3][r]));
            v *= qk_scale;
            v = fmaxf(v, __shfl_xor(v, 1));
            v = fmaxf(v, __shfl_xor(v, 2));
            v = fmaxf(v, __shfl_xor(v, 4));
            v = fmaxf(v, __shfl_xor(v, 8));
            pm[r] = v;
        }
        float corr[4];
        float p[4][4]; // p[n][r]
#pragma unroll
        for (int r = 0; r < 4; ++r) {
            const float mnew = fmaxf(mr[r], pm[r]);
            corr[r] = __expf(mr[r] - mnew);
            mr[r] = mnew;
            float ps = 0.f;
#pragma unroll
            for (int n = 0; n < 4; ++n) {
                const float pv = __expf(s[n][r] * qk_scale - mnew);
                p[n][r] = pv;
                ps += pv;
            }
            ps += __shfl_xor(ps, 1);
            ps += __shfl_xor(ps, 2);
            ps += __shfl_xor(ps, 4);
            ps += __shfl_xor(ps, 8);
            lr[r] = lr[r] * corr[r] + ps;
        }
#pragma unroll
        for (int f = 0; f < 6; ++f)
#pragma unroll
            for (int r = 0; r < 4; ++r) o[f][r] *= corr[r];

        // P -> per-wave LDS (bf16), then PV
#pragma unroll
        for (int n = 0; n < 4; ++n)
#pragma unroll
            for (int r = 0; r < 4; ++r)
                Ps[w * 1024 + (l4 * 4 + r) * 64 + n * 16 + l15] = (bf16_t)p[n][r];
        asm volatile("s_waitcnt lgkmcnt(0)" ::: "memory");

#pragma unroll
        for (int kk = 0; kk < 2; ++kk) {
            bf16x8 pa = *(const bf16x8*)(Ps + w * 1024 + l15 * 64 + kk * 32 + l4 * 8);
#pragma unroll
            for (int f = 0; f < 6; ++f) {
                bf16x8 vb = *(const bf16x8*)(Vt + (f * 16 + l15) * 64 + kk * 32 + l4 * 8);
                o[f] = MFMA_BF16(pa, vb, o[f]);
            }
        }
    }

    // epilogue: ctx = O / l, in place over QC
#pragma unroll
    for (int f = 0; f < 6; ++f)
#pragma unroll
        for (int r = 0; r < 4; ++r) {
            const int row = q0 + l4 * 4 + r;
            QC[((size_t)row * B + b) * D + h * HD + f * 16 + l15] = (bf16_t)(o[f][r] / lr[r]);
        }
}

// ---------------------------------------------------------------------------
// Window aggregation for the text part (one wave per (b, t)), fp32 in, bf16 out.
// two : window 3, anchor = text[t]
// three: window 5, anchor = text[t+1] (zero row at t = T-1)
// weight_k = dot(anchor, win_k) / (max(|anchor|,eps) * max(|win_k|,eps));
// out-of-range rows are zero -> dot 0 -> weight 0 (matches jnp.pad semantics).
// ---------------------------------------------------------------------------
__global__ void window_kernel(const float* __restrict__ q,
                              bf16_t* __restrict__ two_q,
                              bf16_t* __restrict__ three_q)
{
    constexpr int T = 316, B = 32, D = 768, NR = 196;
    constexpr float EPS = 1e-8f;
    const int tp = blockIdx.x, b = blockIdx.y, lane = threadIdx.x;

    float val[5][12];
#pragma unroll
    for (int w = 0; w < 5; ++w) {
        const int tt = tp + w - 2;
        const bool ok = (tt >= 0 && tt < T);
#pragma unroll
        for (int j = 0; j < 12; ++j) {
            const int c = lane + 64 * j;
            val[w][j] = ok ? q[((size_t)(NR + tt) * B + b) * D + c] : 0.f;
        }
    }
    float nrm[5], d2[3], d3[5];
#pragma unroll
    for (int w = 0; w < 5; ++w) {
        float s = 0.f;
        for (int j = 0; j < 12; ++j) s += val[w][j] * val[w][j];
        nrm[w] = s;
    }
#pragma unroll
    for (int k = 0; k < 3; ++k) {
        float s = 0.f;
        for (int j = 0; j < 12; ++j) s += val[2][j] * val[k + 1][j];
        d2[k] = s;
    }
#pragma unroll
    for (int k = 0; k < 5; ++k) {
        float s = 0.f;
        for (int j = 0; j < 12; ++j) s += val[3][j] * val[k][j];
        d3[k] = s;
    }
    // wave-wide reductions
#pragma unroll
    for (int w = 0; w < 5; ++w)
        for (int m = 1; m < 64; m <<= 1) nrm[w] += __shfl_xor(nrm[w], m);
#pragma unroll
    for (int k = 0; k < 3; ++k)
        for (int m = 1; m < 64; m <<= 1) d2[k] += __shfl_xor(d2[k], m);
#pragma unroll
    for (int k = 0; k < 5; ++k)
        for (int m = 1; m < 64; m <<= 1) d3[k] += __shfl_xor(d3[k], m);

    const float na2 = fmaxf(sqrtf(nrm[2]), EPS);
    const float na3 = fmaxf(sqrtf(nrm[3]), EPS);
    float w2[3], w3[5];
#pragma unroll
    for (int k = 0; k < 3; ++k) w2[k] = d2[k] / (na2 * fmaxf(sqrtf(nrm[k + 1]), EPS));
#pragma unroll
    for (int k = 0; k < 5; ++k) w3[k] = d3[k] / (na3 * fmaxf(sqrtf(nrm[k]), EPS));

#pragma unroll
    for (int j = 0; j < 12; ++j) {
        float o2 = 0.f, o3 = 0.f;
#pragma unroll
        for (int k = 0; k < 3; ++k) o2 += w2[k] * val[k + 1][j];
#pragma unroll
        for (int k = 0; k < 5; ++k) o3 += w3[k] * val[k][j];
        const int c = lane + 64 * j;
        const size_t idx = ((size_t)(NR + tp) * B + b) * D + c;
        two_q[idx] = (bf16_t)o2;
        three_q[idx] = (bf16_t)o3;
    }
}

// visual rows (l < 196) are copied unchanged (bf16) into two_q / three_q
__global__ void copy_visual(const bf16_t* __restrict__ qb,
                            bf16_t* __restrict__ two_q,
                            bf16_t* __restrict__ three_q)
{
    const size_t i = (size_t)blockIdx.x * blockDim.x + threadIdx.x;
    const size_t n = (size_t)196 * 32 * 768 / 8;
    if (i < n) {
        bf16x8 v = *((const bf16x8*)qb + i);
        *((bf16x8*)two_q + i) = v;
        *((bf16x8*)three_q + i) = v;
    }
}

extern "C" void kernel_launch(void* const* d_in, const int* in_sizes, int n_in,
                              void* d_out, int out_size, void* d_ws, size_t ws_size,
                              hipStream_t stream)
{
    const float* query  = (const float*)d_in[0];
    const float* key    = (const float*)d_in[1];
    const float* value  = (const float*)d_in[2];
    const float* w_in[3]  = {(const float*)d_in[3], (const float*)d_in[5], (const float*)d_in[7]};
    const float* w_out[3] = {(const float*)d_in[4], (const float*)d_in[6], (const float*)d_in[8]};
    const float* alpha  = (const float*)d_in[9];
    const float* beta   = (const float*)d_in[10];
    const float* gamma  = (const float*)d_in[11];
    float* out = (float*)d_out;

    const size_t NE = (size_t)512 * 32 * 768;   // 12.58M elements
    const size_t WSZ = (size_t)768 * 768;       // one weight matrix
    bf16_t* qb      = (bf16_t*)d_ws;            // bf16 query
    bf16_t* kb      = qb + NE;
    bf16_t* vb      = kb + NE;
    bf16_t* two_q   = vb + NE;
    bf16_t* three_q = two_q + NE;
    bf16_t* QP      = three_q + NE;             // also holds ctx (in-place)
    bf16_t* KP      = QP + NE;
    bf16_t* VP      = KP + NE;
    bf16_t* wb_in[3]  = {VP + NE, VP + NE + 3 * WSZ, VP + NE + 6 * WSZ};
    bf16_t* wb_out[3] = {VP + NE + 9 * WSZ, VP + NE + 10 * WSZ, VP + NE + 11 * WSZ};

    // fp32 -> bf16 conversions
    const int cb = 256;
    convert_kernel<<<(int)(NE / 8 + cb - 1) / cb, cb, 0, stream>>>(query, qb, (int)(NE / 8));
    convert_kernel<<<(int)(NE / 8 + cb - 1) / cb, cb, 0, stream>>>(key, kb, (int)(NE / 8));
    convert_kernel<<<(int)(NE / 8 + cb - 1) / cb, cb, 0, stream>>>(value, vb, (int)(NE / 8));
    for (int i = 0; i < 3; ++i) {
        convert_kernel<<<(int)(3 * WSZ / 8 + cb - 1) / cb, cb, 0, stream>>>(w_in[i], wb_in[i], (int)(3 * WSZ / 8));
        convert_kernel<<<(int)(WSZ / 8 + cb - 1) / cb, cb, 0, stream>>>(w_out[i], wb_out[i], (int)(WSZ / 8));
    }

    const int M = 512 * 32, D = 768;
    const dim3 ggrid(M / 128, D / 128);

    copy_visual<<<2352, 256, 0, stream>>>(qb, two_q, three_q);
    window_kernel<<<dim3(316, 32), 64, 0, stream>>>(query, two_q, three_q);

    // branch order: 2 (writes out), 3, 1 (both accumulate)
    const bf16_t* qins[3] = {two_q, three_q, qb};
    const int     wsel[3] = {1, 2, 0};
    for (int i = 0; i < 3; ++i) {
        const int s = wsel[i];
        gemm_bt<bf16_t><<<ggrid, 256, 0, stream>>>(qins[i], wb_in[s], QP, M, D, D, nullptr, 0);
        gemm_bt<bf16_t><<<ggrid, 256, 0, stream>>>(kb, wb_in[s] + WSZ, KP, M, D, D, nullptr, 0);
        gemm_bt<bf16_t><<<ggrid, 256, 0, stream>>>(vb, wb_in[s] + 2 * WSZ, VP, M, D, D, nullptr, 0);
        attn_kernel<<<dim3(8, 8, 32), 256, 0, stream>>>(QP, KP, VP);
        const float* sc = (s == 0) ? alpha : (s == 1) ? beta : gamma;
        gemm_bt<float><<<ggrid, 256, 0, stream>>>(QP, wb_out[s], out, M, D, D, sc, i > 0 ? 1 : 0);
    }
}

// Round 4
// 977.396 us; speedup vs baseline: 1.1311x; 1.1311x over previous
//
#include <hip/hip_runtime.h>
#include <cstdint>
#include <cstddef>

typedef __bf16 bf16_t;
typedef float f32x4 __attribute__((ext_vector_type(4)));
typedef __bf16 bf16x8 __attribute__((ext_vector_type(8)));

#define MFMA_BF16(a, b, c) __builtin_amdgcn_mfma_f32_16x16x32_bf16((a), (b), (c), 0, 0, 0)

// async global->LDS, 16B per lane; LDS dest = wave-uniform base + lane*16
#define GLDS16(gp, lp) __builtin_amdgcn_global_load_lds(                      \
    (const __attribute__((address_space(1))) void*)(gp),                      \
    (__attribute__((address_space(3))) void*)(lp), 16, 0, 0)

// ---------------------------------------------------------------------------
// fp32 -> bf16 convert, 8 elements/thread
// ---------------------------------------------------------------------------
__global__ void convert_kernel(const float* __restrict__ src,
                               bf16_t* __restrict__ dst, int n8)
{
    const int i = blockIdx.x * blockDim.x + threadIdx.x;
    if (i < n8) {
        const float4* s = (const float4*)src + (size_t)i * 2;
        const float4 a = s[0], b = s[1];
        bf16x8 v = {(bf16_t)a.x, (bf16_t)a.y, (bf16_t)a.z, (bf16_t)a.w,
                    (bf16_t)b.x, (bf16_t)b.y, (bf16_t)b.z, (bf16_t)b.w};
        *((bf16x8*)dst + i) = v;
    }
}

// ---------------------------------------------------------------------------
// C[M,N] = scale * (A[M,K] @ W[N,K]^T)  (+ C if accumulate)
// 128x128 tile, BK=32, 4 waves 2x2. Staging via global_load_lds dwordx4
// (m97 structure). Fragment layouts per learn_hip m89/m91.
// ---------------------------------------------------------------------------
template <typename CT>
__global__ __launch_bounds__(256) void gemm_bt(const bf16_t* __restrict__ A,
                                               const bf16_t* __restrict__ W,
                                               CT* C,
                                               int M, int N, int K,
                                               const float* __restrict__ scale_ptr,
                                               int accumulate)
{
    __shared__ bf16_t As[128 * 32];
    __shared__ bf16_t Ws[128 * 32];
    const int t = threadIdx.x;
    const int lane = t & 63;
    const int w = t >> 6;
    const int wr = (w >> 1) * 64;
    const int wc = (w & 1) * 64;
    const int tm = blockIdx.x * 128, tn = blockIdx.y * 128;
    const int l15 = lane & 15, l4 = lane >> 4;

    const f32x4 fzero = {0.f, 0.f, 0.f, 0.f};
    f32x4 acc[4][4];
#pragma unroll
    for (int i = 0; i < 4; ++i)
#pragma unroll
        for (int j = 0; j < 4; ++j) acc[i][j] = fzero;

    // staging map: thread t covers tile elems [t*8, t*8+8) and +2048 (lane-linear)
    const int ar0 = t >> 2, ac0 = (t & 3) * 8;
    const int ar1 = ar0 + 64;

    for (int kb = 0; kb < K; kb += 32) {
        __syncthreads();   // previous iteration's ds_reads complete
        GLDS16(A + (size_t)(tm + ar0) * K + kb + ac0, (char*)As + w * 1024);
        GLDS16(A + (size_t)(tm + ar1) * K + kb + ac0, (char*)As + 4096 + w * 1024);
        GLDS16(W + (size_t)(tn + ar0) * K + kb + ac0, (char*)Ws + w * 1024);
        GLDS16(W + (size_t)(tn + ar1) * K + kb + ac0, (char*)Ws + 4096 + w * 1024);
        __syncthreads();   // barrier drains vmcnt(0) -> LDS tiles ready
        bf16x8 af[4], bfr[4];
#pragma unroll
        for (int i = 0; i < 4; ++i)
            af[i] = *(const bf16x8*)(As + (wr + i * 16 + l15) * 32 + l4 * 8);
#pragma unroll
        for (int j = 0; j < 4; ++j)
            bfr[j] = *(const bf16x8*)(Ws + (wc + j * 16 + l15) * 32 + l4 * 8);
#pragma unroll
        for (int i = 0; i < 4; ++i)
#pragma unroll
            for (int j = 0; j < 4; ++j)
                acc[i][j] = MFMA_BF16(af[i], bfr[j], acc[i][j]);
    }

    const float scale = scale_ptr ? scale_ptr[0] : 1.0f;
#pragma unroll
    for (int i = 0; i < 4; ++i) {
#pragma unroll
        for (int j = 0; j < 4; ++j) {
            const int col = tn + wc + j * 16 + l15;
#pragma unroll
            for (int r = 0; r < 4; ++r) {
                const int row = tm + wr + i * 16 + l4 * 4 + r;
                const size_t idx = (size_t)row * N + col;
                float v = acc[i][j][r] * scale;
                if (accumulate) v += (float)C[idx];
                C[idx] = (CT)v;
            }
        }
    }
}

// ---------------------------------------------------------------------------
// Flash attention, one block per (h,b): 512 thr = 8 waves, wave w owns q rows
// [w*64, w*64+64). K/V staged ONCE per block (no cross-block re-fetch).
// KVBLK=64, 8 k-tiles. ctx written in place over QC (Q frags hoisted first).
// LDS: Ks[64][96] (glds, linear), Vt[96][64] XOR-swizzled transpose,
// Ps[8][2][16][64] XOR-swizzled P staging. Swizzles use bits>=3 so b128
// reads stay contiguous; write/read banks ~2-way (free, m136).
// ---------------------------------------------------------------------------
__global__ __launch_bounds__(512, 2) void attn_kernel(bf16_t* QC,
                                                      const bf16_t* __restrict__ Kp,
                                                      const bf16_t* __restrict__ Vp)
{
    constexpr int B = 32, HD = 96, D = 768;
    __shared__ bf16_t Ks[64 * 96];
    __shared__ bf16_t Vt[96 * 64];
    __shared__ bf16_t Ps[8][2][16 * 64];

    const int h = blockIdx.x, b = blockIdx.y;
    const int t = threadIdx.x, lane = t & 63, w = t >> 6;
    const int l15 = lane & 15, l4 = lane >> 4;
    const float qk_scale = 0.10206207261596575f; // 1/sqrt(96)

    // Q fragments: 4 m-frags x 3 k-steps, rows w*64 + m*16 + l15
    bf16x8 aq[4][3];
#pragma unroll
    for (int m = 0; m < 4; ++m)
#pragma unroll
        for (int kk = 0; kk < 3; ++kk)
            aq[m][kk] = *(const bf16x8*)(QC + ((size_t)(w * 64 + m * 16 + l15) * B + b) * D
                                         + h * HD + kk * 32 + l4 * 8);

    const f32x4 fzero = {0.f, 0.f, 0.f, 0.f};
    f32x4 o[4][6];
#pragma unroll
    for (int m = 0; m < 4; ++m)
#pragma unroll
        for (int f = 0; f < 6; ++f) o[m][f] = fzero;
    float mr[4][4], lr[4][4];
#pragma unroll
    for (int m = 0; m < 4; ++m)
#pragma unroll
        for (int r = 0; r < 4; ++r) { mr[m][r] = -1e30f; lr[m][r] = 0.f; }

    // staging map: tile = 64x96 = 6144 elems; round0: all threads (4096),
    // round1: waves 0..3 (2048). rr = elem/96, cc = elem%96.
    const int f0 = t * 8;
    const int rr0 = f0 / 96, cc0 = f0 % 96;
    const int f1 = 4096 + t * 8;
    const int rr1 = f1 / 96, cc1 = f1 % 96;
    const int sv0 = ((cc0 >> 3) & 7) << 3;
    const int sv1 = ((cc1 >> 3) & 7) << 3;

    for (int kt = 0; kt < 8; ++kt) {
        const int k0 = kt * 64;
        __syncthreads();   // previous tile's LDS reads complete
        // K -> LDS (async, lane-linear dest)
        GLDS16(Kp + ((size_t)(k0 + rr0) * B + b) * D + h * HD + cc0,
               (char*)Ks + w * 1024);
        if (w < 4)
            GLDS16(Kp + ((size_t)(k0 + rr1) * B + b) * D + h * HD + cc1,
                   (char*)Ks + 8192 + w * 1024);
        // V -> regs -> transposed+swizzled LDS
        bf16x8 v0 = *(const bf16x8*)(Vp + ((size_t)(k0 + rr0) * B + b) * D + h * HD + cc0);
        {
            const int colsw = rr0 ^ sv0;
#pragma unroll
            for (int j = 0; j < 8; ++j)
                Vt[(cc0 + j) * 64 + colsw] = v0[j];
        }
        if (w < 4) {
            bf16x8 v1 = *(const bf16x8*)(Vp + ((size_t)(k0 + rr1) * B + b) * D + h * HD + cc1);
            const int colsw = rr1 ^ sv1;
#pragma unroll
            for (int j = 0; j < 8; ++j)
                Vt[(cc1 + j) * 64 + colsw] = v1[j];
        }
        __syncthreads();   // drains vmcnt (K glds) + lgkm (Vt stores)

#pragma unroll
        for (int mp = 0; mp < 2; ++mp) {
            // S = Q K^T for m-pair (2 x 16 rows x 64 kpos)
            f32x4 s[2][4];
#pragma unroll
            for (int mi = 0; mi < 2; ++mi)
#pragma unroll
                for (int n = 0; n < 4; ++n) s[mi][n] = fzero;
#pragma unroll
            for (int kk = 0; kk < 3; ++kk)
#pragma unroll
                for (int n = 0; n < 4; ++n) {
                    bf16x8 kf = *(const bf16x8*)(Ks + (n * 16 + l15) * 96 + kk * 32 + l4 * 8);
                    s[0][n] = MFMA_BF16(aq[2 * mp][kk], kf, s[0][n]);
                    s[1][n] = MFMA_BF16(aq[2 * mp + 1][kk], kf, s[1][n]);
                }
            // online softmax; lane owns rows 4*l4+r, col l15 per n-frag
#pragma unroll
            for (int mi = 0; mi < 2; ++mi) {
                const int m = 2 * mp + mi;
#pragma unroll
                for (int r = 0; r < 4; ++r) {
                    float v = fmaxf(fmaxf(s[mi][0][r], s[mi][1][r]),
                                    fmaxf(s[mi][2][r], s[mi][3][r]));
                    v *= qk_scale;
                    v = fmaxf(v, __shfl_xor(v, 1));
                    v = fmaxf(v, __shfl_xor(v, 2));
                    v = fmaxf(v, __shfl_xor(v, 4));
                    v = fmaxf(v, __shfl_xor(v, 8));
                    const float mnew = fmaxf(mr[m][r], v);
                    const float corr = __expf(mr[m][r] - mnew);
                    mr[m][r] = mnew;
                    const int row = 4 * l4 + r;
                    float ps = 0.f;
#pragma unroll
                    for (int n = 0; n < 4; ++n) {
                        const float pv = __expf(s[mi][n][r] * qk_scale - mnew);
                        ps += pv;
                        Ps[w][mi][row * 64 + ((n * 16 + l15) ^ ((row & 7) << 3))] = (bf16_t)pv;
                    }
                    ps += __shfl_xor(ps, 1);
                    ps += __shfl_xor(ps, 2);
                    ps += __shfl_xor(ps, 4);
                    ps += __shfl_xor(ps, 8);
                    lr[m][r] = lr[m][r] * corr + ps;
#pragma unroll
                    for (int f = 0; f < 6; ++f) o[m][f][r] *= corr;
                }
            }
            asm volatile("s_waitcnt lgkmcnt(0)" ::: "memory");
            __builtin_amdgcn_sched_barrier(0);
            // PV: hoist P frags, then accumulate over f
            bf16x8 pa[2][2];
#pragma unroll
            for (int mi = 0; mi < 2; ++mi)
#pragma unroll
                for (int kk = 0; kk < 2; ++kk)
                    pa[mi][kk] = *(const bf16x8*)(&Ps[w][mi][l15 * 64 +
                                  ((kk * 32 + l4 * 8) ^ ((l15 & 7) << 3))]);
#pragma unroll
            for (int f = 0; f < 6; ++f) {
                const int c = f * 16 + l15;
                const int sv = ((c >> 3) & 7) << 3;
#pragma unroll
                for (int kk = 0; kk < 2; ++kk) {
                    bf16x8 vbf = *(const bf16x8*)(Vt + c * 64 + ((kk * 32 + l4 * 8) ^ sv));
                    o[2 * mp][f]     = MFMA_BF16(pa[0][kk], vbf, o[2 * mp][f]);
                    o[2 * mp + 1][f] = MFMA_BF16(pa[1][kk], vbf, o[2 * mp + 1][f]);
                }
            }
        }
    }

    // epilogue: ctx = O / l, in place over QC
#pragma unroll
    for (int m = 0; m < 4; ++m)
#pragma unroll
        for (int f = 0; f < 6; ++f)
#pragma unroll
            for (int r = 0; r < 4; ++r) {
                const int row = w * 64 + m * 16 + 4 * l4 + r;
                QC[((size_t)row * B + b) * D + h * HD + f * 16 + l15] =
                    (bf16_t)(o[m][f][r] / lr[m][r]);
            }
}

// ---------------------------------------------------------------------------
// Window aggregation (text rows), fp32 in, bf16 out. One wave per (b,t).
// ---------------------------------------------------------------------------
__global__ void window_kernel(const float* __restrict__ q,
                              bf16_t* __restrict__ two_q,
                              bf16_t* __restrict__ three_q)
{
    constexpr int T = 316, B = 32, D = 768, NR = 196;
    constexpr float EPS = 1e-8f;
    const int tp = blockIdx.x, b = blockIdx.y, lane = threadIdx.x;

    float val[5][12];
#pragma unroll
    for (int w = 0; w < 5; ++w) {
        const int tt = tp + w - 2;
        const bool ok = (tt >= 0 && tt < T);
#pragma unroll
        for (int j = 0; j < 12; ++j) {
            const int c = lane + 64 * j;
            val[w][j] = ok ? q[((size_t)(NR + tt) * B + b) * D + c] : 0.f;
        }
    }
    float nrm[5], d2[3], d3[5];
#pragma unroll
    for (int w = 0; w < 5; ++w) {
        float s = 0.f;
        for (int j = 0; j < 12; ++j) s += val[w][j] * val[w][j];
        nrm[w] = s;
    }
#pragma unroll
    for (int k = 0; k < 3; ++k) {
        float s = 0.f;
        for (int j = 0; j < 12; ++j) s += val[2][j] * val[k + 1][j];
        d2[k] = s;
    }
#pragma unroll
    for (int k = 0; k < 5; ++k) {
        float s = 0.f;
        for (int j = 0; j < 12; ++j) s += val[3][j] * val[k][j];
        d3[k] = s;
    }
#pragma unroll
    for (int w = 0; w < 5; ++w)
        for (int m = 1; m < 64; m <<= 1) nrm[w] += __shfl_xor(nrm[w], m);
#pragma unroll
    for (int k = 0; k < 3; ++k)
        for (int m = 1; m < 64; m <<= 1) d2[k] += __shfl_xor(d2[k], m);
#pragma unroll
    for (int k = 0; k < 5; ++k)
        for (int m = 1; m < 64; m <<= 1) d3[k] += __shfl_xor(d3[k], m);

    const float na2 = fmaxf(sqrtf(nrm[2]), EPS);
    const float na3 = fmaxf(sqrtf(nrm[3]), EPS);
    float w2[3], w3[5];
#pragma unroll
    for (int k = 0; k < 3; ++k) w2[k] = d2[k] / (na2 * fmaxf(sqrtf(nrm[k + 1]), EPS));
#pragma unroll
    for (int k = 0; k < 5; ++k) w3[k] = d3[k] / (na3 * fmaxf(sqrtf(nrm[k]), EPS));

#pragma unroll
    for (int j = 0; j < 12; ++j) {
        float o2 = 0.f, o3 = 0.f;
#pragma unroll
        for (int k = 0; k < 3; ++k) o2 += w2[k] * val[k + 1][j];
#pragma unroll
        for (int k = 0; k < 5; ++k) o3 += w3[k] * val[k][j];
        const int c = lane + 64 * j;
        const size_t idx = ((size_t)(NR + tp) * B + b) * D + c;
        two_q[idx] = (bf16_t)o2;
        three_q[idx] = (bf16_t)o3;
    }
}

// visual rows (l < 196) copied unchanged (bf16) into two_q / three_q
__global__ void copy_visual(const bf16_t* __restrict__ qb,
                            bf16_t* __restrict__ two_q,
                            bf16_t* __restrict__ three_q)
{
    const size_t i = (size_t)blockIdx.x * blockDim.x + threadIdx.x;
    const size_t n = (size_t)196 * 32 * 768 / 8;
    if (i < n) {
        bf16x8 v = *((const bf16x8*)qb + i);
        *((bf16x8*)two_q + i) = v;
        *((bf16x8*)three_q + i) = v;
    }
}

extern "C" void kernel_launch(void* const* d_in, const int* in_sizes, int n_in,
                              void* d_out, int out_size, void* d_ws, size_t ws_size,
                              hipStream_t stream)
{
    const float* query  = (const float*)d_in[0];
    const float* key    = (const float*)d_in[1];
    const float* value  = (const float*)d_in[2];
    const float* w_in[3]  = {(const float*)d_in[3], (const float*)d_in[5], (const float*)d_in[7]};
    const float* w_out[3] = {(const float*)d_in[4], (const float*)d_in[6], (const float*)d_in[8]};
    const float* alpha  = (const float*)d_in[9];
    const float* beta   = (const float*)d_in[10];
    const float* gamma  = (const float*)d_in[11];
    float* out = (float*)d_out;

    const size_t NE = (size_t)512 * 32 * 768;
    const size_t WSZ = (size_t)768 * 768;
    bf16_t* qb      = (bf16_t*)d_ws;
    bf16_t* kb      = qb + NE;
    bf16_t* vb      = kb + NE;
    bf16_t* two_q   = vb + NE;
    bf16_t* three_q = two_q + NE;
    bf16_t* QP      = three_q + NE;   // also holds ctx (in-place)
    bf16_t* KP      = QP + NE;
    bf16_t* VP      = KP + NE;
    bf16_t* wb_in[3]  = {VP + NE, VP + NE + 3 * WSZ, VP + NE + 6 * WSZ};
    bf16_t* wb_out[3] = {VP + NE + 9 * WSZ, VP + NE + 10 * WSZ, VP + NE + 11 * WSZ};

    const int cb = 256;
    convert_kernel<<<(int)(NE / 8 + cb - 1) / cb, cb, 0, stream>>>(query, qb, (int)(NE / 8));
    convert_kernel<<<(int)(NE / 8 + cb - 1) / cb, cb, 0, stream>>>(key, kb, (int)(NE / 8));
    convert_kernel<<<(int)(NE / 8 + cb - 1) / cb, cb, 0, stream>>>(value, vb, (int)(NE / 8));
    for (int i = 0; i < 3; ++i) {
        convert_kernel<<<(int)(3 * WSZ / 8 + cb - 1) / cb, cb, 0, stream>>>(w_in[i], wb_in[i], (int)(3 * WSZ / 8));
        convert_kernel<<<(int)(WSZ / 8 + cb - 1) / cb, cb, 0, stream>>>(w_out[i], wb_out[i], (int)(WSZ / 8));
    }

    const int M = 512 * 32, D = 768;
    const dim3 ggrid(M / 128, D / 128);

    copy_visual<<<2352, 256, 0, stream>>>(qb, two_q, three_q);
    window_kernel<<<dim3(316, 32), 64, 0, stream>>>(query, two_q, three_q);

    // branch order: 2 (writes out), 3, 1 (both accumulate)
    const bf16_t* qins[3] = {two_q, three_q, qb};
    const int     wsel[3] = {1, 2, 0};
    for (int i = 0; i < 3; ++i) {
        const int s = wsel[i];
        gemm_bt<bf16_t><<<ggrid, 256, 0, stream>>>(qins[i], wb_in[s], QP, M, D, D, nullptr, 0);
        gemm_bt<bf16_t><<<ggrid, 256, 0, stream>>>(kb, wb_in[s] + WSZ, KP, M, D, D, nullptr, 0);
        gemm_bt<bf16_t><<<ggrid, 256, 0, stream>>>(vb, wb_in[s] + 2 * WSZ, VP, M, D, D, nullptr, 0);
        attn_kernel<<<dim3(8, 32), 512, 0, stream>>>(QP, KP, VP);
        const float* sc = (s == 0) ? alpha : (s == 1) ? beta : gamma;
        gemm_bt<float><<<ggrid, 256, 0, stream>>>(QP, wb_out[s], out, M, D, D, sc, i > 0 ? 1 : 0);
    }
}